// Round 13
// baseline (25.778 us; speedup 1.0000x reference)
//
#include <hip/hip_runtime.h>

typedef float f32x4 __attribute__((ext_vector_type(4)));

#define TPB 256
#define PPB 128             // points per block (2 lanes cooperate per point)
#define NBLK 1364           // 174592 / 128
#define TPB_F 1024
#define GNUM 50
#define INF_ 1000000.0f
#define L2E  1.44269504088896f
#define C_STREAM 0.519860385f   // 0.75 * ln2

// Focal-loss element math for the target-correction, in terms of a=|x|:
//   e = exp(-a), ln = log(1+e), s = 1/(1+e)
//   s2 = s^2 ; apl = a+ln = softplus(a) ; bb = e^2 * ln
__device__ __forceinline__ void sp_parts(float xx, float& s2, float& apl, float& bb) {
    float a  = fabsf(xx);
    float e  = __expf(-a);
    float t  = 1.0f + e;
    float r  = __builtin_amdgcn_rcpf(t);
    float ln = __logf(t);
    s2  = r * r;
    apl = a + ln;
    bb  = e * e * ln;
}

// Streaming: p^2 * log2(1+e^x)  (0.75*ln2 applied once per thread)
// gfx950: __builtin_amdgcn_exp2f = v_exp_f32 = 2^x; __builtin_amdgcn_logf = v_log_f32 = log2(x)
__device__ __forceinline__ float stream_elem(float x, float acc) {
    float t = __builtin_amdgcn_exp2f(x * L2E);     // e^x
    float u = 1.0f + t;
    float p = t * __builtin_amdgcn_rcpf(u);        // sigmoid(x)
    float lg = __builtin_amdgcn_logf(u);           // log2(1+e^x)
    return fmaf(p * p, lg, acc);
}

__global__ __launch_bounds__(TPB, 2) void fcos_fused(
    const float* __restrict__ pred_class,
    const float4* __restrict__ pred_bbox,
    const float* __restrict__ pred_ctr,
    const float4* __restrict__ gt_boxes,
    const int* __restrict__ gt_labels,
    float* __restrict__ partials)
{
    __shared__ float wpart[4][5];

    const int tid = threadIdx.x;
    const int sub = tid & 1;        // 2 lanes cooperate on one point
    const int pt  = tid >> 1;       // local point 0..127
    const int k   = (blockIdx.x << 7) + pt;

    // ---- (1) issue ALL stream loads first: HBM fetch starts at t=0 ----
    const f32x4* pc4 = (const f32x4*)pred_class + (size_t)blockIdx.x * 2560;
    f32x4 v[10];
    #pragma unroll
    for (int it = 0; it < 10; ++it) v[it] = pc4[tid + it * TPB];

    // point loads (pair-duplicated address, same cacheline — harmless)
    float4 dpred = pred_bbox[k];
    float  pcv   = pred_ctr[k];

    // ---- (2) per-point decode + 25-box scan per sub-lane (covers load latency) ----
    int li, b, p;
    if (k < 131072)      { li = 0; b = k >> 14;               p = k & 16383; }
    else if (k < 163840) { li = 1; int t = k - 131072; b = t >> 12; p = t & 4095; }
    else if (k < 172032) { li = 2; int t = k - 163840; b = t >> 10; p = t & 1023; }
    else if (k < 174080) { li = 3; int t = k - 172032; b = t >> 8;  p = t & 255; }
    else                 { li = 4; int t = k - 174080; b = t >> 6;  p = t & 63; }

    const int logn = 7 - li;
    const float sF = (float)(8 << li);
    const float x = ((float)(p & ((1 << logn) - 1)) + 0.5f) * sF;
    const float y = ((float)(p >> logn) + 0.5f) * sF;
    const float lo = (li == 0) ? -1.0f : (float)(64 << (li - 1));
    const float hi = (li == 4) ? INF_ : (float)(64 << li);

    const float4* gb = gt_boxes + b * GNUM;
    float best = INF_;
    int bi = GNUM;
    #pragma unroll 5
    for (int j = 0; j < 25; ++j) {
        int g = sub * 25 + j;       // contiguous chunk preserves argmin ordering
        float4 bx = gb[g];
        float l  = x - bx.x;
        float t  = y - bx.y;
        float rr = bx.z - x;
        float bt = bx.w - y;
        float mn = fminf(fminf(l, t), fminf(rr, bt));
        float mx = fmaxf(fmaxf(l, t), fmaxf(rr, bt));
        float area = (bx.z - bx.x) * (bx.w - bx.y);
        bool ok = (mn > 0.0f) && (mx >= lo) && (mx <= hi);
        float m = ok ? area : INF_;
        if (m < best) { best = m; bi = g; }
    }
    {   // lexicographic (area, idx) merge across the 2 sub-lanes
        float ob = __shfl_xor(best, 1);
        int   oi = __shfl_xor(bi, 1);
        if (ob < best || (ob == best && oi < bi)) { best = ob; bi = oi; }
    }

    // ---- (3) positive-point math on sub==0 ----
    const bool pos = best < INF_;
    float ctr = 0.0f, lbox = 0.0f, bce = 0.0f, posf = 0.0f, cls = 0.0f;
    if (sub == 0 && pos) {
        posf = 1.0f;
        int lab = gt_labels[b * GNUM + bi] - 1;                 // 0..79
        float xx = pred_class[(size_t)k * 80 + lab];            // gather issued early
        float4 bx = gb[bi];
        float wl = x - bx.x, wt = y - bx.y, wr = bx.z - x, wb = bx.w - y;

        float num = fminf(wl, wr) * fminf(wt, wb);
        float den = fmaxf(wl, wr) * fmaxf(wt, wb) + 1e-12f;
        ctr = __builtin_amdgcn_sqrtf(
                  fminf(fmaxf(num * __builtin_amdgcn_rcpf(den), 0.0f), 1.0f));

        float px1 = x - dpred.x, py1 = y - dpred.y, px2 = x + dpred.z, py2 = y + dpred.w;
        float tx1 = x - wl,  ty1 = y - wt,  tx2 = x + wr,  ty2 = y + wb;
        float ix1 = fmaxf(px1, tx1), iy1 = fmaxf(py1, ty1);
        float ix2 = fminf(px2, tx2), iy2 = fminf(py2, ty2);
        float inter = fmaxf(ix2 - ix1, 0.0f) * fmaxf(iy2 - iy1, 0.0f);
        float ap = fmaxf(px2 - px1, 0.0f) * fmaxf(py2 - py1, 0.0f);
        float at = fmaxf(tx2 - tx1, 0.0f) * fmaxf(ty2 - ty1, 0.0f);
        float iou = inter * __builtin_amdgcn_rcpf(ap + at - inter + 1e-7f);
        lbox = -__logf(fminf(fmaxf(iou, 1e-6f), 1.0f)) * ctr;

        float e  = __expf(-fabsf(pcv));
        float l1 = __logf(1.0f + e);
        float sp_p = fmaxf(pcv, 0.0f) + l1;
        float sp_n = fmaxf(-pcv, 0.0f) + l1;
        bce = ctr * sp_n + (1.0f - ctr) * sp_p;

        // correction: stream adds 0.75*nontarget for the target elem; true = 0.25*target
        float s2c, aplc, bbc;
        sp_parts(xx, s2c, aplc, bbc);
        float nt = (xx >= 0.0f) ? aplc : bbc;
        float tg = (xx >= 0.0f) ? bbc : aplc;
        cls = s2c * fmaf(0.25f, tg, -0.75f * nt);
    }

    // ---- (4) consume the stream (label-free focal for all 40 elements) ----
    float a0 = 0.f, a1 = 0.f, a2 = 0.f, a3 = 0.f;
    #pragma unroll
    for (int it = 0; it < 10; ++it) {
        a0 = stream_elem(v[it].x, a0);
        a1 = stream_elem(v[it].y, a1);
        a2 = stream_elem(v[it].z, a2);
        a3 = stream_elem(v[it].w, a3);
    }
    cls = fmaf(C_STREAM, (a0 + a1) + (a2 + a3), cls);

    // ---- (5) deterministic block reduction of 5 sums ----
    float v5[5] = {cls, lbox, bce, posf, ctr};
    #pragma unroll
    for (int off = 32; off >= 1; off >>= 1) {
        #pragma unroll
        for (int s2 = 0; s2 < 5; ++s2) v5[s2] += __shfl_down(v5[s2], off);
    }
    const int lane = tid & 63, wid = tid >> 6;
    if (lane == 0) {
        #pragma unroll
        for (int s2 = 0; s2 < 5; ++s2) wpart[wid][s2] = v5[s2];
    }
    __syncthreads();
    if (tid == 0) {
        #pragma unroll
        for (int s2 = 0; s2 < 5; ++s2)
            partials[s2 * NBLK + blockIdx.x] =
                (wpart[0][s2] + wpart[1][s2]) + (wpart[2][s2] + wpart[3][s2]);
    }
}

__global__ __launch_bounds__(TPB_F) void fcos_final(
    const float* __restrict__ partials, float* __restrict__ out)
{
    const int tid = threadIdx.x;
    float acc[5] = {0, 0, 0, 0, 0};
    for (int i = tid; i < NBLK; i += TPB_F) {
        #pragma unroll
        for (int s2 = 0; s2 < 5; ++s2) acc[s2] += partials[s2 * NBLK + i];
    }
    #pragma unroll
    for (int off = 32; off >= 1; off >>= 1) {
        #pragma unroll
        for (int s2 = 0; s2 < 5; ++s2) acc[s2] += __shfl_down(acc[s2], off);
    }
    __shared__ float wp[16][5];
    const int lane = tid & 63, wid = tid >> 6;
    if (lane == 0) {
        #pragma unroll
        for (int s2 = 0; s2 < 5; ++s2) wp[wid][s2] = acc[s2];
    }
    __syncthreads();
    if (tid == 0) {
        float S[5];
        #pragma unroll
        for (int s2 = 0; s2 < 5; ++s2) {
            float s = 0.0f;
            #pragma unroll
            for (int w = 0; w < 16; ++w) s += wp[w][s2];
            S[s2] = s;
        }
        float pos_num = fmaxf(S[3], 1.0f);
        float denorm  = fmaxf(S[4], 1e-6f);
        out[0] = S[0] / pos_num;   // loss_cls
        out[1] = S[1] / denorm;    // loss_box
        out[2] = S[2] / pos_num;   // loss_ctr
    }
}

extern "C" void kernel_launch(void* const* d_in, const int* in_sizes, int n_in,
                              void* d_out, int out_size, void* d_ws, size_t ws_size,
                              hipStream_t stream) {
    const float*  pred_class = (const float*)d_in[0];
    const float4* pred_bbox  = (const float4*)d_in[1];
    const float*  pred_ctr   = (const float*)d_in[2];
    const float4* gt_boxes   = (const float4*)d_in[3];
    const int*    gt_labels  = (const int*)d_in[4];
    float* partials = (float*)d_ws;          // 5 * NBLK floats, fully rewritten
    float* out = (float*)d_out;

    fcos_fused<<<NBLK, TPB, 0, stream>>>(pred_class, pred_bbox, pred_ctr,
                                         gt_boxes, gt_labels, partials);
    fcos_final<<<1, TPB_F, 0, stream>>>(partials, out);
}

// Round 14
// 22.734 us; speedup vs baseline: 1.1339x; 1.1339x over previous
//
#include <hip/hip_runtime.h>

typedef float f32x4 __attribute__((ext_vector_type(4)));

#define TPB 256
#define ABLK 682            // assignment blocks: 1 thread per point
#define SBLK 852            // streaming blocks: 4096 float4s each (16 per thread)
#define GRID 1534
#define TPB_F 1024
#define GNUM 50
#define INF_ 1000000.0f
#define L2E  1.44269504088896f
#define C_STREAM 0.519860385f   // 0.75 * ln2
// stream f4 total = 174592*20 = 3,491,840 = 852*4096 + 2048; the 2048-f4 tail is
// handled by assign blocks 0..7 (1 extra f4 per thread).
#define TAIL_BASE (SBLK * 4096)
// partials: [0..3409] assign 5x682 ; [3410 .. 3410+852*4) stream per-wave sums
#define PSTREAM 3410
#define NPART (PSTREAM + SBLK * 4)

// Focal-loss element math for the target-correction, in terms of a=|x|:
//   e = exp(-a), ln = log(1+e), s = 1/(1+e); s2=s^2, apl=softplus(a), bb=e^2*ln
__device__ __forceinline__ void sp_parts(float xx, float& s2, float& apl, float& bb) {
    float a  = fabsf(xx);
    float e  = __expf(-a);
    float t  = 1.0f + e;
    float r  = __builtin_amdgcn_rcpf(t);
    float ln = __logf(t);
    s2  = r * r;
    apl = a + ln;
    bb  = e * e * ln;
}

// Streaming: p^2 * log2(1+e^x)   (0.75*ln2 applied at fold/finalize)
__device__ __forceinline__ float stream_elem(float x, float acc) {
    float t = __builtin_amdgcn_exp2f(x * L2E);     // e^x
    float u = 1.0f + t;
    float p = t * __builtin_amdgcn_rcpf(u);        // sigmoid(x)
    float lg = __builtin_amdgcn_logf(u);           // log2(1+e^x)
    return fmaf(p * p, lg, acc);
}

__global__ __launch_bounds__(TPB) void fcos_fat(
    const float* __restrict__ pred_class,
    const float4* __restrict__ pred_bbox,
    const float* __restrict__ pred_ctr,
    const float4* __restrict__ gt_boxes,
    const int* __restrict__ gt_labels,
    float* __restrict__ partials)
{
    const int tid = threadIdx.x;
    const int bid = blockIdx.x;
    const int lane = tid & 63, wid = tid >> 6;
    const f32x4* pc4 = (const f32x4*)pred_class;

    if (bid >= ABLK) {
        // ============ streaming block: 16 float4 in flight per thread ============
        const int s = bid - ABLK;             // 0..851
        const f32x4* base = pc4 + (size_t)s * 4096;
        f32x4 v[16];
        #pragma unroll
        for (int it = 0; it < 16; ++it) v[it] = base[tid + it * TPB];

        float a0 = 0.f, a1 = 0.f, a2 = 0.f, a3 = 0.f;
        #pragma unroll
        for (int it = 0; it < 16; ++it) {
            a0 = stream_elem(v[it].x, a0);
            a1 = stream_elem(v[it].y, a1);
            a2 = stream_elem(v[it].z, a2);
            a3 = stream_elem(v[it].w, a3);
        }
        float acc = (a0 + a1) + (a2 + a3);
        #pragma unroll
        for (int off = 32; off >= 1; off >>= 1) acc += __shfl_down(acc, off);
        if (lane == 0) partials[PSTREAM + s * 4 + wid] = acc;  // per-wave, no barrier
    } else {
        // ============ assignment block: 1 thread per point (+ stream tail) ============
        __shared__ float wpart[4][5];
        const int a = bid;                    // 0..681
        const int k = (a << 8) + tid;

        // tail stream f4 for blocks 0..7 (issued first: latency hides under scan)
        f32x4 tv = {0.f, 0.f, 0.f, 0.f};
        const bool has_tail = (a < 8);
        if (has_tail) tv = pc4[TAIL_BASE + (a << 8) + tid];

        float4 dpred = pred_bbox[k];
        float  pcv   = pred_ctr[k];

        int li, b, p;
        if (k < 131072)      { li = 0; b = k >> 14;               p = k & 16383; }
        else if (k < 163840) { li = 1; int t = k - 131072; b = t >> 12; p = t & 4095; }
        else if (k < 172032) { li = 2; int t = k - 163840; b = t >> 10; p = t & 1023; }
        else if (k < 174080) { li = 3; int t = k - 172032; b = t >> 8;  p = t & 255; }
        else                 { li = 4; int t = k - 174080; b = t >> 6;  p = t & 63; }

        const int logn = 7 - li;
        const float sF = (float)(8 << li);
        const float x = ((float)(p & ((1 << logn) - 1)) + 0.5f) * sF;
        const float y = ((float)(p >> logn) + 0.5f) * sF;
        const float lo = (li == 0) ? -1.0f : (float)(64 << (li - 1));
        const float hi = (li == 4) ? INF_ : (float)(64 << li);

        const float4* gb = gt_boxes + b * GNUM;
        float best = INF_;
        int bi = 0;
        #pragma unroll 5
        for (int g = 0; g < GNUM; ++g) {
            float4 bx = gb[g];
            float l  = x - bx.x;
            float t  = y - bx.y;
            float rr = bx.z - x;
            float bt = bx.w - y;
            float mn = fminf(fminf(l, t), fminf(rr, bt));
            float mx = fmaxf(fmaxf(l, t), fmaxf(rr, bt));
            float area = (bx.z - bx.x) * (bx.w - bx.y);
            bool ok = (mn > 0.0f) && (mx >= lo) && (mx <= hi);
            float m = ok ? area : INF_;
            if (m < best) { best = m; bi = g; }
        }

        const bool pos = best < INF_;
        float ctr = 0.0f, lbox = 0.0f, bce = 0.0f, posf = 0.0f, cls = 0.0f;
        if (pos) {
            posf = 1.0f;
            int lab = gt_labels[b * GNUM + bi] - 1;
            float xx = pred_class[(size_t)k * 80 + lab];
            float4 bx = gb[bi];
            float wl = x - bx.x, wt = y - bx.y, wr = bx.z - x, wb = bx.w - y;

            float num = fminf(wl, wr) * fminf(wt, wb);
            float den = fmaxf(wl, wr) * fmaxf(wt, wb) + 1e-12f;
            ctr = __builtin_amdgcn_sqrtf(
                      fminf(fmaxf(num * __builtin_amdgcn_rcpf(den), 0.0f), 1.0f));

            float px1 = x - dpred.x, py1 = y - dpred.y, px2 = x + dpred.z, py2 = y + dpred.w;
            float tx1 = x - wl,  ty1 = y - wt,  tx2 = x + wr,  ty2 = y + wb;
            float ix1 = fmaxf(px1, tx1), iy1 = fmaxf(py1, ty1);
            float ix2 = fminf(px2, tx2), iy2 = fminf(py2, ty2);
            float inter = fmaxf(ix2 - ix1, 0.0f) * fmaxf(iy2 - iy1, 0.0f);
            float ap = fmaxf(px2 - px1, 0.0f) * fmaxf(py2 - py1, 0.0f);
            float at = fmaxf(tx2 - tx1, 0.0f) * fmaxf(ty2 - ty1, 0.0f);
            float iou = inter * __builtin_amdgcn_rcpf(ap + at - inter + 1e-7f);
            lbox = -__logf(fminf(fmaxf(iou, 1e-6f), 1.0f)) * ctr;

            float e  = __expf(-fabsf(pcv));
            float l1 = __logf(1.0f + e);
            float sp_p = fmaxf(pcv, 0.0f) + l1;
            float sp_n = fmaxf(-pcv, 0.0f) + l1;
            bce = ctr * sp_n + (1.0f - ctr) * sp_p;

            float s2c, aplc, bbc;
            sp_parts(xx, s2c, aplc, bbc);
            float nt = (xx >= 0.0f) ? aplc : bbc;
            float tg = (xx >= 0.0f) ? bbc : aplc;
            cls = s2c * fmaf(0.25f, tg, -0.75f * nt);
        }

        if (has_tail) {
            float ta = stream_elem(tv.x, 0.f);
            ta = stream_elem(tv.y, ta);
            ta = stream_elem(tv.z, ta);
            ta = stream_elem(tv.w, ta);
            cls = fmaf(C_STREAM, ta, cls);      // pre-scale: finalize divides by pos_num
        }

        float v5[5] = {cls, lbox, bce, posf, ctr};
        #pragma unroll
        for (int off = 32; off >= 1; off >>= 1) {
            #pragma unroll
            for (int s2 = 0; s2 < 5; ++s2) v5[s2] += __shfl_down(v5[s2], off);
        }
        if (lane == 0) {
            #pragma unroll
            for (int s2 = 0; s2 < 5; ++s2) wpart[wid][s2] = v5[s2];
        }
        __syncthreads();
        if (tid == 0) {
            #pragma unroll
            for (int s2 = 0; s2 < 5; ++s2)
                partials[s2 * ABLK + a] =
                    (wpart[0][s2] + wpart[1][s2]) + (wpart[2][s2] + wpart[3][s2]);
        }
    }
}

__global__ __launch_bounds__(TPB_F) void fcos_final(
    const float* __restrict__ partials, float* __restrict__ out)
{
    const int tid = threadIdx.x;
    float acc[5] = {0, 0, 0, 0, 0};
    float accs = 0.0f;
    for (int i = tid; i < ABLK; i += TPB_F) {
        #pragma unroll
        for (int s2 = 0; s2 < 5; ++s2) acc[s2] += partials[s2 * ABLK + i];
    }
    for (int i = tid; i < SBLK * 4; i += TPB_F) accs += partials[PSTREAM + i];
    #pragma unroll
    for (int off = 32; off >= 1; off >>= 1) {
        #pragma unroll
        for (int s2 = 0; s2 < 5; ++s2) acc[s2] += __shfl_down(acc[s2], off);
        accs += __shfl_down(accs, off);
    }
    __shared__ float wp[16][6];
    const int lane = tid & 63, wid = tid >> 6;
    if (lane == 0) {
        #pragma unroll
        for (int s2 = 0; s2 < 5; ++s2) wp[wid][s2] = acc[s2];
        wp[wid][5] = accs;
    }
    __syncthreads();
    if (tid == 0) {
        float S[6];
        #pragma unroll
        for (int s2 = 0; s2 < 6; ++s2) {
            float s = 0.0f;
            #pragma unroll
            for (int w = 0; w < 16; ++w) s += wp[w][s2];
            S[s2] = s;
        }
        float pos_num = fmaxf(S[3], 1.0f);
        float denorm  = fmaxf(S[4], 1e-6f);
        out[0] = fmaf(C_STREAM, S[5], S[0]) / pos_num;  // loss_cls
        out[1] = S[1] / denorm;                         // loss_box
        out[2] = S[2] / pos_num;                        // loss_ctr
    }
}

extern "C" void kernel_launch(void* const* d_in, const int* in_sizes, int n_in,
                              void* d_out, int out_size, void* d_ws, size_t ws_size,
                              hipStream_t stream) {
    const float*  pred_class = (const float*)d_in[0];
    const float4* pred_bbox  = (const float4*)d_in[1];
    const float*  pred_ctr   = (const float*)d_in[2];
    const float4* gt_boxes   = (const float4*)d_in[3];
    const int*    gt_labels  = (const int*)d_in[4];
    float* partials = (float*)d_ws;          // NPART floats, fully rewritten
    float* out = (float*)d_out;

    fcos_fat<<<GRID, TPB, 0, stream>>>(pred_class, pred_bbox, pred_ctr,
                                       gt_boxes, gt_labels, partials);
    fcos_final<<<1, TPB_F, 0, stream>>>(partials, out);
}